// Round 12
// baseline (154.770 us; speedup 1.0000x reference)
//
#include <hip/hip_runtime.h>
#include <math.h>

#define BATCH  2048
#define FEAT   2048
#define LUTSZ  64
#define TF     64           // features per tile (lut tile = 16 KB)
#define GROUPS 32           // batch groups
#define RPB    64           // rows per block = BATCH/GROUPS
#define WAVES  8
#define RPW    8            // rows per wave

typedef float f32x2 __attribute__((ext_vector_type(2)));
typedef int   i32x2 __attribute__((ext_vector_type(2)));
typedef float f32x4 __attribute__((ext_vector_type(4)));

// ---------------------------------------------------------------------------
// Round-12 = round-11 structure at TF=64: LDS 128KB -> 80KB exactly, so
// 2 blocks/CU -> 16 waves/CU (4/SIMD), attacking the r11 occupancy cliff
// (18.8%, 2 waves/SIMD, latency-bound: ~12us/layer/CU of pure stall).
//
//  * LDS: 16KB lut tile (sigmoid applied during staging, exact f32 chain)
//         + 8 x 8KB wave-private x rows = 80KB.
//  * x re-read amplification 8x -> 32x, but x (16.8MB) is L2/L3-resident;
//    grid is tile-fastest so all 32 tiles of a group are co-resident and
//    rows stay L2-hot. HBM FETCH predicted unchanged (~115MB/layer).
//  * everything else proven: ballot transpose (r9), wave fences (r7),
//    depth-1 row prefetch (r11), no barriers after sl staging, no NT (r10).
//
// Numerics locked (absmax 0.0 r4/5/7/8/9/11): layer-1 (v+1.0f)*0.5f;
// sigmoid = 1.0f/(1.0f + RN32(exp_f64(-v))); f32 compares.
// ---------------------------------------------------------------------------

__device__ __forceinline__ void wave_fence() {
    __builtin_amdgcn_sched_barrier(0);
    __builtin_amdgcn_wave_barrier();
    __builtin_amdgcn_sched_barrier(0);
}

template<int L>   // 0: transform-in + sigmoid-lut; 1: sigmoid-lut; 2: raw lut
__global__ __launch_bounds__(512, 4) void lut_tile_kernel(
    const float* __restrict__ xin, const float* __restrict__ rr,
    const int* __restrict__ connect, const float* __restrict__ lutg,
    float* __restrict__ yout)
{
    __shared__ float sl[TF * LUTSZ];          // 16 KiB lut tile
    __shared__ f32x4 xr4[WAVES][FEAT / 4];    // 64 KiB wave-private x rows

    const int tile = blockIdx.x;
    const int grp  = blockIdx.y;
    const int f0   = tile * TF;
    const int tid  = threadIdx.x;
    const int lane = tid & 63;
    const int w    = tid >> 6;

    // ---- stage lut tile (+ exact f32-chain sigmoid for L<2) ----
    for (int i = tid; i < TF * LUTSZ; i += 512) {
        float v = lutg[(size_t)f0 * LUTSZ + i];
        if (L < 2) {
            float e = (float)exp(-(double)v);   // correctly-rounded f32 exp
            v = 1.0f / (1.0f + e);              // f32 IEEE chain
        }
        sl[i] = v;
    }

    // ---- connect regs (scrambled ballot layout), once per block ----
    i32x2 cc0, cc1, cc2;
    {
        const i32x2* cg = reinterpret_cast<const i32x2*>(
            connect + (size_t)f0 * 6);
        cc0 = cg[lane]; cc1 = cg[64 + lane]; cc2 = cg[128 + lane];
    }

    const int b0 = grp * RPB + w * RPW;
    const float* xw = reinterpret_cast<const float*>(xr4[w]);

    // ---- prefetch row 0 (x, r) ----
    f32x4 nx[8];
    f32x2 nr0, nr1, nr2;
    {
        const f32x4* xg = reinterpret_cast<const f32x4*>(xin + (size_t)b0 * FEAT);
        #pragma unroll
        for (int j = 0; j < 8; ++j) nx[j] = xg[j * 64 + lane];
        const f32x2* rg = reinterpret_cast<const f32x2*>(
            rr + ((size_t)b0 * FEAT + f0) * 6);
        nr0 = rg[lane]; nr1 = rg[64 + lane]; nr2 = rg[128 + lane];
    }

    __syncthreads();   // sl visible; no block barriers after this

    for (int i = 0; i < RPW; ++i) {
        const int b = b0 + i;

        const f32x2 cr0 = nr0, cr1 = nr1, cr2 = nr2;

        // ---- write x row to wave-private LDS (WAR fence vs prev gathers) ----
        wave_fence();
        #pragma unroll
        for (int j = 0; j < 8; ++j) {
            f32x4 v = nx[j];
            if (L == 0) v = (v + 1.0f) * 0.5f;   // exact f32 chain, layer 1
            xr4[w][j * 64 + lane] = v;
        }
        wave_fence();

        // ---- prefetch next row (latency hides under compute) ----
        if (i + 1 < RPW) {
            const int bn = b + 1;
            const f32x4* xg = reinterpret_cast<const f32x4*>(
                xin + (size_t)bn * FEAT);
            #pragma unroll
            for (int j = 0; j < 8; ++j) nx[j] = xg[j * 64 + lane];
            const f32x2* rg = reinterpret_cast<const f32x2*>(
                rr + ((size_t)bn * FEAT + f0) * 6);
            nr0 = rg[lane]; nr1 = rg[64 + lane]; nr2 = rg[128 + lane];
        }

        // ---- ballot transpose (r9-verified) + LDS lut gather ----
        const unsigned long long B0 = __ballot(xw[cc0[0]] >= cr0[0]);
        const unsigned long long B1 = __ballot(xw[cc0[1]] >= cr0[1]);
        const unsigned long long B2 = __ballot(xw[cc1[0]] >= cr1[0]);
        const unsigned long long B3 = __ballot(xw[cc1[1]] >= cr1[1]);
        const unsigned long long B4 = __ballot(xw[cc2[0]] >= cr2[0]);
        const unsigned long long B5 = __ballot(xw[cc2[1]] >= cr2[1]);

        int idx = 0;
        #pragma unroll
        for (int j = 0; j < 6; ++j) {
            const int e = 6 * lane + j;          // even => e&1 == j&1
            const int g = e >> 7;
            const unsigned long long src =
                (j & 1) ? ((g == 0) ? B1 : (g == 1) ? B3 : B5)
                        : ((g == 0) ? B0 : (g == 1) ? B2 : B4);
            idx |= (int)((src >> ((e & 127) >> 1)) & 1ull) << j;
        }

        const float v = sl[lane * LUTSZ + idx];
        yout[(size_t)b * FEAT + f0 + lane] = v;
    }
}

extern "C" void kernel_launch(void* const* d_in, const int* in_sizes, int n_in,
                              void* d_out, int out_size, void* d_ws, size_t ws_size,
                              hipStream_t stream) {
    const float* inputs = (const float*)d_in[0];
    const float* r1     = (const float*)d_in[1];
    const float* r2     = (const float*)d_in[2];
    const float* r3     = (const float*)d_in[3];
    const float* lut1   = (const float*)d_in[4];
    const float* lut2   = (const float*)d_in[5];
    const float* lut3   = (const float*)d_in[6];
    const int*   c1     = (const int*)d_in[7];
    const int*   c2     = (const int*)d_in[8];
    const int*   c3     = (const int*)d_in[9];
    float* out = (float*)d_out;

    const size_t n = (size_t)BATCH * FEAT;
    float* ws1 = (float*)d_ws;        // [BATCH, FEAT] f32 (proven ws window)
    float* ws2 = ws1 + n;

    // tile-fastest grid: all 32 tiles of a group co-resident -> x rows L2-hot
    dim3 grid(FEAT / TF, GROUPS), block(512);
    lut_tile_kernel<0><<<grid, block, 0, stream>>>(inputs, r1, c1, lut1, ws1);
    lut_tile_kernel<1><<<grid, block, 0, stream>>>(ws1,    r2, c2, lut2, ws2);
    lut_tile_kernel<2><<<grid, block, 0, stream>>>(ws2,    r3, c3, lut3, out);
}

// Round 13
// 145.639 us; speedup vs baseline: 1.0627x; 1.0627x over previous
//
#include <hip/hip_runtime.h>
#include <math.h>

#define BATCH  2048
#define FEAT   2048
#define LUTSZ  64
#define TF     256
#define NCH    4            // TF/64
#define GROUPS 32
#define RPB    64
#define WAVES  8
#define RPW    8

typedef float f32x2 __attribute__((ext_vector_type(2)));
typedef int   i32x2 __attribute__((ext_vector_type(2)));
typedef float f32x4 __attribute__((ext_vector_type(4)));

// ---------------------------------------------------------------------------
// Round-13: same-run A/B/C structural ablation across the three dispatches.
//   L1 = V_A: r11 verbatim (LDS x + LDS slut + ballot)          [control]
//   L2 = V_B: global x-gathers, no staging, 64KB LDS, 16 waves  [gather-home]
//   L3 = V_C: naive strided per-lane r/c + direct compares      [machinery?]
// All three use the locked numerics: layer-1 (v+1.0f)*0.5f; sigmoid =
// 1.0f/(1.0f + RN32(exp_f64(-v))) applied during lut staging; f32 compares.
// ---------------------------------------------------------------------------

__device__ __forceinline__ void wave_fence() {
    __builtin_amdgcn_sched_barrier(0);
    __builtin_amdgcn_wave_barrier();
    __builtin_amdgcn_sched_barrier(0);
}

// ============================ V_A (layer 1) ================================
__global__ __launch_bounds__(512, 2) void va_kernel(
    const float* __restrict__ xin, const float* __restrict__ rr,
    const int* __restrict__ connect, const float* __restrict__ lutg,
    float* __restrict__ yout)
{
    __shared__ float sl[TF * LUTSZ];          // 64 KiB
    __shared__ f32x4 xr4[WAVES][FEAT / 4];    // 64 KiB

    const int tile = blockIdx.x, grp = blockIdx.y;
    const int f0 = tile * TF;
    const int tid = threadIdx.x, lane = tid & 63, w = tid >> 6;

    for (int i = tid; i < TF * LUTSZ; i += 512) {
        float v = lutg[(size_t)f0 * LUTSZ + i];
        float e = (float)exp(-(double)v);
        sl[i] = 1.0f / (1.0f + e);
    }

    i32x2 cc[NCH][3];
    #pragma unroll
    for (int t = 0; t < NCH; ++t) {
        const i32x2* cg = reinterpret_cast<const i32x2*>(
            connect + (size_t)(f0 + t * 64) * 6);
        cc[t][0] = cg[lane]; cc[t][1] = cg[64 + lane]; cc[t][2] = cg[128 + lane];
    }

    const int b0 = grp * RPB + w * RPW;
    const float* xw = reinterpret_cast<const float*>(xr4[w]);

    f32x4 nx[8];
    f32x2 nr[NCH][3];
    {
        const f32x4* xg = reinterpret_cast<const f32x4*>(xin + (size_t)b0 * FEAT);
        #pragma unroll
        for (int j = 0; j < 8; ++j) nx[j] = xg[j * 64 + lane];
        #pragma unroll
        for (int t = 0; t < NCH; ++t) {
            const f32x2* rg = reinterpret_cast<const f32x2*>(
                rr + ((size_t)b0 * FEAT + f0 + t * 64) * 6);
            nr[t][0] = rg[lane]; nr[t][1] = rg[64 + lane]; nr[t][2] = rg[128 + lane];
        }
    }
    __syncthreads();

    for (int i = 0; i < RPW; ++i) {
        const int b = b0 + i;
        f32x2 cr[NCH][3];
        #pragma unroll
        for (int t = 0; t < NCH; ++t) {
            cr[t][0] = nr[t][0]; cr[t][1] = nr[t][1]; cr[t][2] = nr[t][2];
        }

        wave_fence();
        #pragma unroll
        for (int j = 0; j < 8; ++j) {
            f32x4 v = nx[j];
            v = (v + 1.0f) * 0.5f;            // layer-1 transform
            xr4[w][j * 64 + lane] = v;
        }
        wave_fence();

        if (i + 1 < RPW) {
            const int bn = b + 1;
            const f32x4* xg = reinterpret_cast<const f32x4*>(
                xin + (size_t)bn * FEAT);
            #pragma unroll
            for (int j = 0; j < 8; ++j) nx[j] = xg[j * 64 + lane];
            #pragma unroll
            for (int t = 0; t < NCH; ++t) {
                const f32x2* rg = reinterpret_cast<const f32x2*>(
                    rr + ((size_t)bn * FEAT + f0 + t * 64) * 6);
                nr[t][0] = rg[lane]; nr[t][1] = rg[64 + lane];
                nr[t][2] = rg[128 + lane];
            }
        }

        #pragma unroll
        for (int t = 0; t < NCH; ++t) {
            const unsigned long long B0 = __ballot(xw[cc[t][0][0]] >= cr[t][0][0]);
            const unsigned long long B1 = __ballot(xw[cc[t][0][1]] >= cr[t][0][1]);
            const unsigned long long B2 = __ballot(xw[cc[t][1][0]] >= cr[t][1][0]);
            const unsigned long long B3 = __ballot(xw[cc[t][1][1]] >= cr[t][1][1]);
            const unsigned long long B4 = __ballot(xw[cc[t][2][0]] >= cr[t][2][0]);
            const unsigned long long B5 = __ballot(xw[cc[t][2][1]] >= cr[t][2][1]);
            int idx = 0;
            #pragma unroll
            for (int j = 0; j < 6; ++j) {
                const int e = 6 * lane + j;
                const int g = e >> 7;
                const unsigned long long src =
                    (j & 1) ? ((g == 0) ? B1 : (g == 1) ? B3 : B5)
                            : ((g == 0) ? B0 : (g == 1) ? B2 : B4);
                idx |= (int)((src >> ((e & 127) >> 1)) & 1ull) << j;
            }
            const float v = sl[(t * 64 + lane) * LUTSZ + idx];
            yout[(size_t)b * FEAT + f0 + t * 64 + lane] = v;
        }
    }
}

// ============================ V_B (layer 2) ================================
// Global x-gathers (row is L1/L2-hot), no x staging, 64 KiB LDS -> 2 blk/CU.
__global__ __launch_bounds__(512, 2) void vb_kernel(
    const float* __restrict__ xin, const float* __restrict__ rr,
    const int* __restrict__ connect, const float* __restrict__ lutg,
    float* __restrict__ yout)
{
    __shared__ float sl[TF * LUTSZ];          // 64 KiB only

    const int tile = blockIdx.x, grp = blockIdx.y;
    const int f0 = tile * TF;
    const int tid = threadIdx.x, lane = tid & 63, w = tid >> 6;

    for (int i = tid; i < TF * LUTSZ; i += 512) {
        float v = lutg[(size_t)f0 * LUTSZ + i];
        float e = (float)exp(-(double)v);
        sl[i] = 1.0f / (1.0f + e);
    }

    i32x2 cc[NCH][3];
    #pragma unroll
    for (int t = 0; t < NCH; ++t) {
        const i32x2* cg = reinterpret_cast<const i32x2*>(
            connect + (size_t)(f0 + t * 64) * 6);
        cc[t][0] = cg[lane]; cc[t][1] = cg[64 + lane]; cc[t][2] = cg[128 + lane];
    }

    const int b0 = grp * RPB + w * RPW;

    f32x2 nr[NCH][3];
    #pragma unroll
    for (int t = 0; t < NCH; ++t) {
        const f32x2* rg = reinterpret_cast<const f32x2*>(
            rr + ((size_t)b0 * FEAT + f0 + t * 64) * 6);
        nr[t][0] = rg[lane]; nr[t][1] = rg[64 + lane]; nr[t][2] = rg[128 + lane];
    }
    __syncthreads();

    for (int i = 0; i < RPW; ++i) {
        const int b = b0 + i;
        const float* xb = xin + (size_t)b * FEAT;

        f32x2 cr[NCH][3];
        #pragma unroll
        for (int t = 0; t < NCH; ++t) {
            cr[t][0] = nr[t][0]; cr[t][1] = nr[t][1]; cr[t][2] = nr[t][2];
        }
        if (i + 1 < RPW) {
            const int bn = b + 1;
            #pragma unroll
            for (int t = 0; t < NCH; ++t) {
                const f32x2* rg = reinterpret_cast<const f32x2*>(
                    rr + ((size_t)bn * FEAT + f0 + t * 64) * 6);
                nr[t][0] = rg[lane]; nr[t][1] = rg[64 + lane];
                nr[t][2] = rg[128 + lane];
            }
        }

        #pragma unroll
        for (int t = 0; t < NCH; ++t) {
            const unsigned long long B0 = __ballot(xb[cc[t][0][0]] >= cr[t][0][0]);
            const unsigned long long B1 = __ballot(xb[cc[t][0][1]] >= cr[t][0][1]);
            const unsigned long long B2 = __ballot(xb[cc[t][1][0]] >= cr[t][1][0]);
            const unsigned long long B3 = __ballot(xb[cc[t][1][1]] >= cr[t][1][1]);
            const unsigned long long B4 = __ballot(xb[cc[t][2][0]] >= cr[t][2][0]);
            const unsigned long long B5 = __ballot(xb[cc[t][2][1]] >= cr[t][2][1]);
            int idx = 0;
            #pragma unroll
            for (int j = 0; j < 6; ++j) {
                const int e = 6 * lane + j;
                const int g = e >> 7;
                const unsigned long long src =
                    (j & 1) ? ((g == 0) ? B1 : (g == 1) ? B3 : B5)
                            : ((g == 0) ? B0 : (g == 1) ? B2 : B4);
                idx |= (int)((src >> ((e & 127) >> 1)) & 1ull) << j;
            }
            const float v = sl[(t * 64 + lane) * LUTSZ + idx];
            yout[(size_t)b * FEAT + f0 + t * 64 + lane] = v;
        }
    }
}

// ============================ V_C (layer 3) ================================
// Naive strided per-lane r/c loads + direct compares; LDS x + LDS raw lut.
__global__ __launch_bounds__(512, 2) void vc_kernel(
    const float* __restrict__ xin, const float* __restrict__ rr,
    const int* __restrict__ connect, const float* __restrict__ lutg,
    float* __restrict__ yout)
{
    __shared__ float sl[TF * LUTSZ];          // 64 KiB (raw lut3)
    __shared__ f32x4 xr4[WAVES][FEAT / 4];    // 64 KiB

    const int tile = blockIdx.x, grp = blockIdx.y;
    const int f0 = tile * TF;
    const int tid = threadIdx.x, lane = tid & 63, w = tid >> 6;

    for (int i = tid; i < TF * LUTSZ; i += 512)
        sl[i] = lutg[(size_t)f0 * LUTSZ + i];

    // natural per-lane connect: lane's feature f = f0 + t*64 + lane
    i32x2 c01[NCH], c23[NCH], c45[NCH];
    #pragma unroll
    for (int t = 0; t < NCH; ++t) {
        const i32x2* cp = reinterpret_cast<const i32x2*>(
            connect + (size_t)(f0 + t * 64 + lane) * 6);
        c01[t] = cp[0]; c23[t] = cp[1]; c45[t] = cp[2];
    }

    const int b0 = grp * RPB + w * RPW;
    const float* xw = reinterpret_cast<const float*>(xr4[w]);

    f32x4 nx[8];
    f32x2 nr0[NCH], nr1[NCH], nr2[NCH];   // strided per-lane r
    {
        const f32x4* xg = reinterpret_cast<const f32x4*>(xin + (size_t)b0 * FEAT);
        #pragma unroll
        for (int j = 0; j < 8; ++j) nx[j] = xg[j * 64 + lane];
        #pragma unroll
        for (int t = 0; t < NCH; ++t) {
            const f32x2* rp = reinterpret_cast<const f32x2*>(
                rr + ((size_t)b0 * FEAT + f0 + t * 64 + lane) * 6);
            nr0[t] = rp[0]; nr1[t] = rp[1]; nr2[t] = rp[2];
        }
    }
    __syncthreads();

    for (int i = 0; i < RPW; ++i) {
        const int b = b0 + i;
        f32x2 r0[NCH], r1[NCH], r2[NCH];
        #pragma unroll
        for (int t = 0; t < NCH; ++t) { r0[t]=nr0[t]; r1[t]=nr1[t]; r2[t]=nr2[t]; }

        wave_fence();
        #pragma unroll
        for (int j = 0; j < 8; ++j) xr4[w][j * 64 + lane] = nx[j];
        wave_fence();

        if (i + 1 < RPW) {
            const int bn = b + 1;
            const f32x4* xg = reinterpret_cast<const f32x4*>(
                xin + (size_t)bn * FEAT);
            #pragma unroll
            for (int j = 0; j < 8; ++j) nx[j] = xg[j * 64 + lane];
            #pragma unroll
            for (int t = 0; t < NCH; ++t) {
                const f32x2* rp = reinterpret_cast<const f32x2*>(
                    rr + ((size_t)bn * FEAT + f0 + t * 64 + lane) * 6);
                nr0[t] = rp[0]; nr1[t] = rp[1]; nr2[t] = rp[2];
            }
        }

        #pragma unroll
        for (int t = 0; t < NCH; ++t) {
            int idx = 0;
            idx |= (xw[c01[t][0]] >= r0[t][0]) ? 1  : 0;
            idx |= (xw[c01[t][1]] >= r0[t][1]) ? 2  : 0;
            idx |= (xw[c23[t][0]] >= r1[t][0]) ? 4  : 0;
            idx |= (xw[c23[t][1]] >= r1[t][1]) ? 8  : 0;
            idx |= (xw[c45[t][0]] >= r2[t][0]) ? 16 : 0;
            idx |= (xw[c45[t][1]] >= r2[t][1]) ? 32 : 0;
            const float v = sl[(t * 64 + lane) * LUTSZ + idx];
            yout[(size_t)b * FEAT + f0 + t * 64 + lane] = v;
        }
    }
}

extern "C" void kernel_launch(void* const* d_in, const int* in_sizes, int n_in,
                              void* d_out, int out_size, void* d_ws, size_t ws_size,
                              hipStream_t stream) {
    const float* inputs = (const float*)d_in[0];
    const float* r1     = (const float*)d_in[1];
    const float* r2     = (const float*)d_in[2];
    const float* r3     = (const float*)d_in[3];
    const float* lut1   = (const float*)d_in[4];
    const float* lut2   = (const float*)d_in[5];
    const float* lut3   = (const float*)d_in[6];
    const int*   c1     = (const int*)d_in[7];
    const int*   c2     = (const int*)d_in[8];
    const int*   c3     = (const int*)d_in[9];
    float* out = (float*)d_out;

    const size_t n = (size_t)BATCH * FEAT;
    float* ws1 = (float*)d_ws;
    float* ws2 = ws1 + n;

    dim3 grid(FEAT / TF, GROUPS), block(512);
    va_kernel<<<grid, block, 0, stream>>>(inputs, r1, c1, lut1, ws1);
    vb_kernel<<<grid, block, 0, stream>>>(ws1,    r2, c2, lut2, ws2);
    vc_kernel<<<grid, block, 0, stream>>>(ws2,    r3, c3, lut3, out);
}

// Round 14
// 124.953 us; speedup vs baseline: 1.2386x; 1.1656x over previous
//
#include <hip/hip_runtime.h>
#include <math.h>

#define BATCH  2048
#define FEAT   2048
#define LUTSZ  64
#define TF     256
#define GROUPS 64
#define RPB    32            // rows per block
#define ITERS  (RPB / 2)     // 2 rows per iteration

typedef float f32x2 __attribute__((ext_vector_type(2)));
typedef int   i32x2 __attribute__((ext_vector_type(2)));
typedef float f32x4 __attribute__((ext_vector_type(4)));

// ---------------------------------------------------------------------------
// Round-14: block-shared x rows -> 80KB LDS -> 2 blocks/CU (the r13 ablation
// showed LDS-gathers must stay (vb slowest) and machinery is neutral (vc~va);
// the remaining lever is overlapping the LDS-pipe phase of one block with the
// HBM phase of another -- impossible at 1 block/CU, which every <=256-block
// variant was stuck at).
//
//  * 8 waves/block: wave w owns (row-slot w>>2, chunk w&3). 2 rows/iter
//    staged cooperatively (16KB, single-buffered, 2 raw barriers per iter --
//    vmem prefetch stays in flight across them).
//  * LDS = 64KB lut tile + 2x8KB x rows = 80KB exactly -> 2 blocks/CU.
//  * grid 8 tiles x 64 groups = 512 blocks (tile-fastest: the 8 tile-blocks
//    of a group share x rows in L2).
//  * slut precomputed in ws when it fits (runtime host check, deterministic);
//    else exp applied during lut staging (both paths proven absmax 0.0).
// Numerics locked: layer-1 (v+1.0f)*0.5f; sigmoid 1.0f/(1.0f+RN32(exp_f64));
// f32 compares; ballot transpose algebra unchanged from r9/r11.
// ---------------------------------------------------------------------------

__device__ __forceinline__ void barrier_keep_vm() {
    __builtin_amdgcn_sched_barrier(0);
    asm volatile("s_waitcnt lgkmcnt(0)\n\ts_barrier" ::: "memory");
    __builtin_amdgcn_sched_barrier(0);
}

__global__ __launch_bounds__(256) void sigmoid_lut_kernel(
    const float* __restrict__ lut1, const float* __restrict__ lut2,
    float* __restrict__ slut1, float* __restrict__ slut2)
{
    const int n = FEAT * LUTSZ;
    int i = blockIdx.x * 256 + threadIdx.x;
    if (i < n) {
        float v = lut1[i];
        float e = (float)exp(-(double)v);
        slut1[i] = 1.0f / (1.0f + e);
    } else {
        i -= n;
        float v = lut2[i];
        float e = (float)exp(-(double)v);
        slut2[i] = 1.0f / (1.0f + e);
    }
}

// L: 0 = transform-in (+sigmoid-lut), 1 = sigmoid-lut, 2 = raw lut
// PRE: lutg already sigmoid'd (slut) -> no exp in staging
template<int L, bool PRE>
__global__ __launch_bounds__(512, 4) void lut_tile2(
    const float* __restrict__ xin, const float* __restrict__ rr,
    const int* __restrict__ connect, const float* __restrict__ lutg,
    float* __restrict__ yout)
{
    __shared__ float sl[TF * LUTSZ];   // 64 KiB
    __shared__ float xsh[2][FEAT];     // 16 KiB  (2 row slots)

    const int tile = blockIdx.x, grp = blockIdx.y;
    const int f0   = tile * TF;
    const int tid  = threadIdx.x, lane = tid & 63, w = tid >> 6;
    const int slot = w >> 2;           // 0/1: which row this wave computes
    const int ch   = w & 3;            // which 64-feature chunk
    const int fc   = f0 + ch * 64;

    // ---- stage lut tile ----
    for (int i = tid; i < TF * LUTSZ; i += 512) {
        float v = lutg[(size_t)f0 * LUTSZ + i];
        if (!PRE && L < 2) {
            float e = (float)exp(-(double)v);   // correctly-rounded f32 exp
            v = 1.0f / (1.0f + e);              // f32 IEEE chain
        }
        sl[i] = v;
    }

    // ---- connect regs for this wave's chunk (scrambled ballot layout) ----
    i32x2 cc0, cc1, cc2;
    {
        const i32x2* cg = reinterpret_cast<const i32x2*>(
            connect + (size_t)fc * 6);
        cc0 = cg[lane]; cc1 = cg[64 + lane]; cc2 = cg[128 + lane];
    }

    const int b0 = grp * RPB;

    // x staging map: thread covers 4 floats at xcol and 4 at xcol+1024 of
    // row (b0 + 2i + xrow_off)  -> conflict-free b128 LDS writes.
    const int xrow_off = tid >> 8;          // 0/1
    const int xcol     = (tid & 255) * 4;   // float offset

    // ---- iter-0 prefetch: x rows 0,1 then r(row slot, iter 0) ----
    f32x4 nxa, nxb;
    {
        const float* xp = xin + (size_t)(b0 + xrow_off) * FEAT;
        nxa = *reinterpret_cast<const f32x4*>(xp + xcol);
        nxb = *reinterpret_cast<const f32x4*>(xp + xcol + 1024);
    }
    f32x2 r0, r1, r2;
    {
        const f32x2* rg = reinterpret_cast<const f32x2*>(
            rr + ((size_t)(b0 + slot) * FEAT + fc) * 6);
        r0 = rg[lane]; r1 = rg[64 + lane]; r2 = rg[128 + lane];
    }
    {
        f32x4 a = nxa, b = nxb;
        if (L == 0) { a = (a + 1.0f) * 0.5f; b = (b + 1.0f) * 0.5f; }
        *reinterpret_cast<f32x4*>(&xsh[xrow_off][xcol])        = a;
        *reinterpret_cast<f32x4*>(&xsh[xrow_off][xcol + 1024]) = b;
    }
    barrier_keep_vm();   // sl + xsh visible to all waves

    for (int i = 0; i < ITERS; ++i) {
        const int b = b0 + 2 * i + slot;

        // ---- prefetch iter i+1: x first, then r (so the x vmcnt-wait at the
        //      LDS write leaves the r loads in flight) ----
        if (i + 1 < ITERS) {
            const float* xp = xin + (size_t)(b0 + 2 * (i + 1) + xrow_off) * FEAT;
            nxa = *reinterpret_cast<const f32x4*>(xp + xcol);
            nxb = *reinterpret_cast<const f32x4*>(xp + xcol + 1024);
        }
        f32x2 n0, n1, n2;
        if (i + 1 < ITERS) {
            const f32x2* rg = reinterpret_cast<const f32x2*>(
                rr + ((size_t)(b + 2) * FEAT + fc) * 6);
            n0 = rg[lane]; n1 = rg[64 + lane]; n2 = rg[128 + lane];
        }

        // ---- ballot transpose (r9-verified) + LDS lut gather ----
        const float* xw = xsh[slot];
        const unsigned long long B0 = __ballot(xw[cc0[0]] >= r0[0]);
        const unsigned long long B1 = __ballot(xw[cc0[1]] >= r0[1]);
        const unsigned long long B2 = __ballot(xw[cc1[0]] >= r1[0]);
        const unsigned long long B3 = __ballot(xw[cc1[1]] >= r1[1]);
        const unsigned long long B4 = __ballot(xw[cc2[0]] >= r2[0]);
        const unsigned long long B5 = __ballot(xw[cc2[1]] >= r2[1]);

        int idx = 0;
        #pragma unroll
        for (int j = 0; j < 6; ++j) {
            const int e = 6 * lane + j;          // even => e&1 == j&1
            const int g = e >> 7;
            const unsigned long long src =
                (j & 1) ? ((g == 0) ? B1 : (g == 1) ? B3 : B5)
                        : ((g == 0) ? B0 : (g == 1) ? B2 : B4);
            idx |= (int)((src >> ((e & 127) >> 1)) & 1ull) << j;
        }

        const float v = sl[(ch * 64 + lane) * LUTSZ + idx];
        yout[(size_t)b * FEAT + fc + lane] = v;

        r0 = n0; r1 = n1; r2 = n2;

        // ---- rotate the shared x buffer ----
        barrier_keep_vm();                // all waves done gathering iter i
        if (i + 1 < ITERS) {
            f32x4 a = nxa, bb = nxb;      // vmcnt-waits x only (r after x)
            if (L == 0) { a = (a + 1.0f) * 0.5f; bb = (bb + 1.0f) * 0.5f; }
            *reinterpret_cast<f32x4*>(&xsh[xrow_off][xcol])        = a;
            *reinterpret_cast<f32x4*>(&xsh[xrow_off][xcol + 1024]) = bb;
            barrier_keep_vm();            // new rows visible
        }
    }
}

extern "C" void kernel_launch(void* const* d_in, const int* in_sizes, int n_in,
                              void* d_out, int out_size, void* d_ws, size_t ws_size,
                              hipStream_t stream) {
    const float* inputs = (const float*)d_in[0];
    const float* r1     = (const float*)d_in[1];
    const float* r2     = (const float*)d_in[2];
    const float* r3     = (const float*)d_in[3];
    const float* lut1   = (const float*)d_in[4];
    const float* lut2   = (const float*)d_in[5];
    const float* lut3   = (const float*)d_in[6];
    const int*   c1     = (const int*)d_in[7];
    const int*   c2     = (const int*)d_in[8];
    const int*   c3     = (const int*)d_in[9];
    float* out = (float*)d_out;

    const size_t n    = (size_t)BATCH * FEAT;
    const size_t lutn = (size_t)FEAT * LUTSZ;
    dim3 grid(FEAT / TF, GROUPS), block(512);

    if (ws_size >= (2 * lutn + 2 * n) * sizeof(float)) {
        float* slut1 = (float*)d_ws;
        float* slut2 = slut1 + lutn;
        float* ws1   = slut2 + lutn;
        float* ws2   = ws1 + n;
        sigmoid_lut_kernel<<<dim3(2 * lutn / 256), dim3(256), 0, stream>>>(
            lut1, lut2, slut1, slut2);
        lut_tile2<0, true ><<<grid, block, 0, stream>>>(inputs, r1, c1, slut1, ws1);
        lut_tile2<1, true ><<<grid, block, 0, stream>>>(ws1,    r2, c2, slut2, ws2);
        lut_tile2<2, true ><<<grid, block, 0, stream>>>(ws2,    r3, c3, lut3,  out);
    } else {
        float* ws1 = (float*)d_ws;
        float* ws2 = ws1 + n;
        lut_tile2<0, false><<<grid, block, 0, stream>>>(inputs, r1, c1, lut1, ws1);
        lut_tile2<1, false><<<grid, block, 0, stream>>>(ws1,    r2, c2, lut2, ws2);
        lut_tile2<2, false><<<grid, block, 0, stream>>>(ws2,    r3, c3, lut3, out);
    }
}